// Round 1
// 326.509 us; speedup vs baseline: 1.0180x; 1.0180x over previous
//
#include <hip/hip_runtime.h>
#include <hip/hip_bf16.h>

#define NPAT 50000
#define NCON 20000
#define NN   70000
#define EE   800000
#define H    128

#define NCON_AL  20032                 // concepts padded to 64-alignment
#define SEGN     (NCON_AL + NPAT)      // 70032 segment ids
#define NBUCK    1095                  // ceil(SEGN/64)
#define RELSPLIT_B 313                 // buckets [0,313) = concept dsts (rel0)
#define BUCKCAP  5120                  // pairs capacity per bucket (max fill ~2900)
#define SUBS     16                    // sub-regions per bucket (reservation slots)
#define SUBCAP   (BUCKCAP / SUBS)      // 320 (max fill ~236)
#define BPE      4096                  // edges per binpack block
#define NBB      ((2 * EE + BPE - 1) / BPE)   // 391
#define CAP      4096                  // aggregate LDS edge capacity (max bucket ~2900)

typedef __attribute__((ext_vector_type(8))) short bf16x8;
typedef __attribute__((ext_vector_type(4))) float f32x4;

__device__ inline unsigned short f2bf(float f) {
    unsigned u = __float_as_uint(f);
    unsigned r = (u + 0x7FFFu + ((u >> 16) & 1u)) >> 16;
    return (unsigned short)r;
}
__device__ inline float bf2f_lo(unsigned v) { return __uint_as_float(v << 16); }
__device__ inline float bf2f_hi(unsigned v) { return __uint_as_float(v & 0xFFFF0000u); }

// ============ init: per-(bucket,sub) cursors at static bases ============
__global__ void init_gcur_kernel(int* __restrict__ gcur) {
    int j = blockIdx.x * 256 + threadIdx.x;
    if (j < NBUCK * SUBS) gcur[j] = (j >> 4) * BUCKCAP + (j & (SUBS - 1)) * SUBCAP;
}

// ============ binpack: 512 thr, LDS counting sort by bucket, run-reserve, write ====
__global__ __launch_bounds__(512) void binpack_kernel(
        const int* __restrict__ dst_pc, const int* __restrict__ src_pc,
        const int* __restrict__ dst_cp, const int* __restrict__ src_cp,
        int* __restrict__ gcur, unsigned* __restrict__ pairs) {
    __shared__ unsigned sval[BPE];           // 16 KB
    __shared__ unsigned short sbkt[BPE];     // 8 KB (bucket id per sorted slot)
    __shared__ int cnt[NBUCK];               // 4.4 KB (then local cursor)
    __shared__ int delta[NBUCK];             // 4.4 KB
    __shared__ int partial[512];
    int t = threadIdx.x, blk = blockIdx.x;
    int base = blk * BPE;
    int n = min(BPE, 2 * EE - base);

    for (int i = t; i < NBUCK; i += 512) cnt[i] = 0;
    __syncthreads();

    unsigned pay[8];
    int bkt[8];
#pragma unroll
    for (int q = 0; q < 8; q++) {
        int li = q * 512 + t;
        bkt[q] = -1;
        if (li < n) {
            int i = base + li;
            int seg, src;
            if (i < EE) { seg = dst_pc[i];                src = src_pc[i]; }
            else        { seg = NCON_AL + dst_cp[i - EE]; src = src_cp[i - EE]; }
            int b = seg >> 6;
            pay[q] = (unsigned)src | ((unsigned)(seg & 63) << 16);
            bkt[q] = b;
            atomicAdd(&cnt[b], 1);
        }
    }
    __syncthreads();

    const int PER = (NBUCK + 511) / 512;   // 3
    int beg = t * PER;
    int s = 0;
#pragma unroll
    for (int k = 0; k < PER; k++) { int i = beg + k; if (i < NBUCK) s += cnt[i]; }
    partial[t] = s;
    __syncthreads();
    for (int o = 1; o < 512; o <<= 1) {
        int v = (t >= o) ? partial[t - o] : 0;
        __syncthreads();
        partial[t] += v;
        __syncthreads();
    }
    int run = partial[t] - s;
    int sub = blk & (SUBS - 1);
    int prefk[PER];
#pragma unroll
    for (int k = 0; k < PER; k++) {
        int i = beg + k;
        if (i < NBUCK) {
            prefk[k] = run;
            int c = cnt[i];
            if (c > 0) {
                int gb = atomicAdd(&gcur[i * SUBS + sub], c);
                delta[i] = gb - run;
            }
            run += c;
        }
    }
    __syncthreads();
#pragma unroll
    for (int k = 0; k < PER; k++) { int i = beg + k; if (i < NBUCK) cnt[i] = prefk[k]; }
    __syncthreads();

#pragma unroll
    for (int q = 0; q < 8; q++) {
        if (bkt[q] >= 0) {
            int b = bkt[q];
            int pos = atomicAdd(&cnt[b], 1);
            sval[pos] = pay[q];
            sbkt[pos] = (unsigned short)b;
        }
    }
    __syncthreads();
    for (int i = t; i < n; i += 512)
        pairs[delta[sbkt[i]] + i] = sval[i];
}

// ============ mean aggregation: block per bucket, 512 thr ============
// gather: 16 lanes cover a 256B row (uint4/lane), 4 edge-slots per wave,
// 2-deep unroll -> 8 independent uint4 loads (32 B/lane) in flight.
#define ACC8(a0, a1, v) \
    a0.x += bf2f_lo((v).x); a0.y += bf2f_hi((v).x); \
    a0.z += bf2f_lo((v).y); a0.w += bf2f_hi((v).y); \
    a1.x += bf2f_lo((v).z); a1.y += bf2f_hi((v).z); \
    a1.z += bf2f_lo((v).w); a1.w += bf2f_hi((v).w);

__global__ __launch_bounds__(512) void aggregate_kernel(
        const unsigned short* __restrict__ xbf, const unsigned* __restrict__ pairs,
        const int* __restrict__ gcur, unsigned short* __restrict__ aggn) {
    __shared__ int cnt64[64];
    __shared__ int soff[65];
    __shared__ int scur[64];
    __shared__ unsigned short ssrc[CAP];
    int t = threadIdx.x, b = blockIdx.x;
    if (t < 64) cnt64[t] = 0;
    __syncthreads();
    // pass A: count per-seg degree over the 16 sub-regions
    for (int s = 0; s < SUBS; s++) {
        int rbase = b * BUCKCAP + s * SUBCAP;
        int rcnt = gcur[b * SUBS + s] - rbase;
        for (int i = t; i < rcnt; i += 512)
            atomicAdd(&cnt64[pairs[rbase + i] >> 16], 1);
    }
    __syncthreads();
    if (t < 64) {  // wave 0: exclusive scan
        int v = cnt64[t];
        int s = v;
#pragma unroll
        for (int o = 1; o < 64; o <<= 1) {
            int u = __shfl_up(s, o);
            if (t >= o) s += u;
        }
        soff[t + 1] = s;
        if (t == 0) soff[0] = 0;
        scur[t] = s - v;
    }
    __syncthreads();
    // pass B: place srcs per-dst-contiguous
    for (int s = 0; s < SUBS; s++) {
        int rbase = b * BUCKCAP + s * SUBCAP;
        int rcnt = gcur[b * SUBS + s] - rbase;
        for (int i = t; i < rcnt; i += 512) {
            unsigned p = pairs[rbase + i];
            int pos = atomicAdd(&scur[p >> 16], 1);
            ssrc[pos] = (unsigned short)(p & 0xFFFF);
        }
    }
    __syncthreads();
    // gather: 8 waves x 8 segs
    int wv = t >> 6, lane = t & 63;
    int g = lane >> 4;          // edge slot 0..3
    int q = lane & 15;          // uint4 index within row (16 B granule)
    int rowbase = (b < RELSPLIT_B) ? 0 : NPAT;
    int seglim  = (b < RELSPLIT_B) ? NCON : SEGN;
    const uint4* xw4 = (const uint4*)xbf;   // 16 x uint4 per row
    for (int i = 0; i < 8; i++) {
        int d = wv * 8 + i;
        int seg = b * 64 + d;
        if (seg >= seglim) continue;
        int beg = soff[d], end = soff[d + 1];
        float4 aA0 = {0.f, 0.f, 0.f, 0.f}, aA1 = {0.f, 0.f, 0.f, 0.f};
        float4 aB0 = {0.f, 0.f, 0.f, 0.f}, aB1 = {0.f, 0.f, 0.f, 0.f};
        int j = beg;
        for (; j + 7 < end; j += 8) {  // 8 edges via 2 independent uint4/lane
            int sA = ssrc[j + g];
            int sB = ssrc[j + 4 + g];
            uint4 vA = xw4[(size_t)(rowbase + sA) * 16 + q];
            uint4 vB = xw4[(size_t)(rowbase + sB) * 16 + q];
            ACC8(aA0, aA1, vA);
            ACC8(aB0, aB1, vB);
        }
        for (; j < end; j += 4) {      // tail: <=2 masked rounds of up to 4 edges
            if (g < end - j) {
                int s0 = ssrc[j + g];
                uint4 v = xw4[(size_t)(rowbase + s0) * 16 + q];
                ACC8(aA0, aA1, v);
            }
        }
        aA0.x += aB0.x; aA0.y += aB0.y; aA0.z += aB0.z; aA0.w += aB0.w;
        aA1.x += aB1.x; aA1.y += aB1.y; aA1.z += aB1.z; aA1.w += aB1.w;
        float r0 = aA0.x, r1 = aA0.y, r2 = aA0.z, r3 = aA0.w;
        float r4 = aA1.x, r5 = aA1.y, r6 = aA1.z, r7 = aA1.w;
        // reduce across the 4 edge-slots (lane bits 4 and 5)
        r0 += __shfl_xor(r0, 16); r1 += __shfl_xor(r1, 16);
        r2 += __shfl_xor(r2, 16); r3 += __shfl_xor(r3, 16);
        r4 += __shfl_xor(r4, 16); r5 += __shfl_xor(r5, 16);
        r6 += __shfl_xor(r6, 16); r7 += __shfl_xor(r7, 16);
        r0 += __shfl_xor(r0, 32); r1 += __shfl_xor(r1, 32);
        r2 += __shfl_xor(r2, 32); r3 += __shfl_xor(r3, 32);
        r4 += __shfl_xor(r4, 32); r5 += __shfl_xor(r5, 32);
        r6 += __shfl_xor(r6, 32); r7 += __shfl_xor(r7, 32);
        if (g == 0) {
            float inv = 1.0f / (float)max(end - beg, 1);
            uint4 o;
            o.x = (unsigned)f2bf(r0 * inv) | ((unsigned)f2bf(r1 * inv) << 16);
            o.y = (unsigned)f2bf(r2 * inv) | ((unsigned)f2bf(r3 * inv) << 16);
            o.z = (unsigned)f2bf(r4 * inv) | ((unsigned)f2bf(r5 * inv) << 16);
            o.w = (unsigned)f2bf(r6 * inv) | ((unsigned)f2bf(r7 * inv) << 16);
            *(uint4*)&aggn[(size_t)seg * H + 8 * q] = o;  // zero-deg segs write 0 (required)
        }
    }
}

// ============ proj GEMM (fp32 VALU): Cbf = A1 @ B1 + bias ============
#define BM 128
#define BK 8

struct GemmJob {
    const float* A1;
    const float* B1;
    const float* bias; unsigned short* Cbf;
    int lda1, K1, M;
};

__global__ void gemm_dual_kernel(GemmJob j0, GemmJob j1, int nb0) {
    __shared__ float sA[BK][BM];
    __shared__ float sB[BK][H];
    bool first = (int)blockIdx.x < nb0;
    GemmJob j = first ? j0 : j1;
    int bm = (first ? blockIdx.x : blockIdx.x - nb0) * BM;
    int tid = threadIdx.x;
    int am = tid >> 1;
    int ak = (tid & 1) * 4;
    int bk = tid >> 5;
    int bn = (tid & 31) * 4;
    int ty = tid >> 4;
    int tx = tid & 15;
    float acc[8][8] = {};
    for (int k0 = 0; k0 < j.K1; k0 += BK) {
        int gm = bm + am; if (gm >= j.M) gm = j.M - 1;
        float4 av = *(const float4*)&j.A1[(size_t)gm * j.lda1 + k0 + ak];
        float4 bv = *(const float4*)&j.B1[(size_t)(k0 + bk) * H + bn];
        __syncthreads();
        sA[ak + 0][am] = av.x; sA[ak + 1][am] = av.y;
        sA[ak + 2][am] = av.z; sA[ak + 3][am] = av.w;
        *(float4*)&sB[bk][bn] = bv;
        __syncthreads();
#pragma unroll
        for (int k = 0; k < BK; k++) {
            float a[8], bb[8];
            *(float4*)&a[0] = *(const float4*)&sA[k][ty * 8];
            *(float4*)&a[4] = *(const float4*)&sA[k][ty * 8 + 4];
            *(float4*)&bb[0] = *(const float4*)&sB[k][tx * 4];
            *(float4*)&bb[4] = *(const float4*)&sB[k][64 + tx * 4];
#pragma unroll
            for (int i = 0; i < 8; i++)
#pragma unroll
                for (int jj = 0; jj < 8; jj++)
                    acc[i][jj] += a[i] * bb[jj];
        }
    }
    float bcol[8];
    *(float4*)&bcol[0] = *(const float4*)&j.bias[tx * 4];
    *(float4*)&bcol[4] = *(const float4*)&j.bias[64 + tx * 4];
#pragma unroll
    for (int i = 0; i < 8; i++) {
        int gr = bm + ty * 8 + i;
        if (gr < j.M) {
#pragma unroll
            for (int q = 0; q < 8; q++) {
                float v = acc[i][q] + bcol[q];
                int gc = (q < 4) ? (tx * 4 + q) : (64 + tx * 4 + q - 4);
                j.Cbf[(size_t)gr * H + gc] = f2bf(v);
            }
        }
    }
}

// ============ layer GEMM (bf16 MFMA): C = [A1|A2] @ bf16([B1;B2]) + bias, relu ======
struct MJob {
    const unsigned short* A1;  // [M][H] bf16
    const unsigned short* A2;  // [M][H] bf16
    const float* B1;           // [H][H] fp32 k-major
    const float* B2;
    const float* bias;
    float* C;                  // fp32 or null
    unsigned short* Cbf;       // bf16 or null
    int M;
};

__global__ __launch_bounds__(256) void gemm_mfma_kernel(MJob j0, MJob j1, int nb0) {
    __shared__ unsigned short sA[128][40];   // [row][k] pad 32->40
    __shared__ unsigned short sBT[128][40];  // [col][k]
    bool first = (int)blockIdx.x < nb0;
    MJob J = first ? j0 : j1;
    int bm = (first ? (int)blockIdx.x : (int)blockIdx.x - nb0) * 128;
    int tid = threadIdx.x;
    int wv = tid >> 6, lane = tid & 63;
    int wr = wv >> 1, wc = wv & 1;
    int m16 = lane & 15, kg = lane >> 4;

    f32x4 acc[4][4];
#pragma unroll
    for (int a = 0; a < 4; a++)
#pragma unroll
        for (int c = 0; c < 4; c++) acc[a][c] = (f32x4){0.f, 0.f, 0.f, 0.f};

    int ar = tid >> 1, ah = tid & 1;
    int gmA = bm + ar; if (gmA >= J.M) gmA = J.M - 1;
    int bn = tid & 127, bk0 = tid >> 7;

#pragma unroll
    for (int kt = 0; kt < 8; kt++) {
        int k0 = kt * 32;
        const unsigned short* asrc = (k0 < 128)
            ? (J.A1 + (size_t)gmA * H + k0)
            : (J.A2 + (size_t)gmA * H + (k0 - 128));
        const uint4* a4 = (const uint4*)(asrc + ah * 16);
        uint4 av0 = a4[0], av1 = a4[1];
        const float* bsrc = (k0 < 128) ? (J.B1 + (size_t)k0 * H)
                                       : (J.B2 + (size_t)(k0 - 128) * H);
        float bvals[16];
#pragma unroll
        for (int kk = 0; kk < 16; kk++) bvals[kk] = bsrc[(size_t)(2 * kk + bk0) * H + bn];
        __syncthreads();
        { uint4* d4 = (uint4*)&sA[ar][ah * 16]; d4[0] = av0; d4[1] = av1; }
#pragma unroll
        for (int kk = 0; kk < 16; kk++) sBT[bn][2 * kk + bk0] = f2bf(bvals[kk]);
        __syncthreads();
        bf16x8 af[4], bfg[4];
#pragma unroll
        for (int mt = 0; mt < 4; mt++)
            af[mt] = *(bf16x8*)&sA[wr * 64 + mt * 16 + m16][kg * 8];
#pragma unroll
        for (int nt = 0; nt < 4; nt++)
            bfg[nt] = *(bf16x8*)&sBT[wc * 64 + nt * 16 + m16][kg * 8];
#pragma unroll
        for (int mt = 0; mt < 4; mt++)
#pragma unroll
            for (int nt = 0; nt < 4; nt++)
                acc[mt][nt] = __builtin_amdgcn_mfma_f32_16x16x32_bf16(
                    af[mt], bfg[nt], acc[mt][nt], 0, 0, 0);
    }
    float bv[4];
#pragma unroll
    for (int nt = 0; nt < 4; nt++) bv[nt] = J.bias[wc * 64 + nt * 16 + m16];
#pragma unroll
    for (int mt = 0; mt < 4; mt++) {
        int gr0 = bm + wr * 64 + mt * 16 + kg * 4;
#pragma unroll
        for (int r = 0; r < 4; r++) {
            int gr = gr0 + r;
            if (gr < J.M) {
#pragma unroll
                for (int nt = 0; nt < 4; nt++) {
                    int gc = wc * 64 + nt * 16 + m16;
                    float v = fmaxf(acc[mt][nt][r] + bv[nt], 0.f);
                    if (J.C)   J.C[(size_t)gr * H + gc] = v;
                    if (J.Cbf) J.Cbf[(size_t)gr * H + gc] = f2bf(v);
                }
            }
        }
    }
}

// ============ launch ============

extern "C" void kernel_launch(void* const* d_in, const int* in_sizes, int n_in,
                              void* d_out, int out_size, void* d_ws, size_t ws_size,
                              hipStream_t stream) {
    const float* x_patient = (const float*)d_in[0];
    const float* x_concept = (const float*)d_in[1];
    const float* W_p       = (const float*)d_in[2];
    const float* b_p       = (const float*)d_in[3];
    const float* W_c       = (const float*)d_in[4];
    const float* b_c       = (const float*)d_in[5];
    const float* W_root    = (const float*)d_in[6];
    const float* b_root    = (const float*)d_in[7];
    const float* W_rel     = (const float*)d_in[8];
    const int*   src_pc    = (const int*)d_in[9];
    const int*   dst_pc    = (const int*)d_in[10];
    const int*   src_cp    = (const int*)d_in[11];
    const int*   dst_cp    = (const int*)d_in[12];
    float* out = (float*)d_out;

    char* w = (char*)d_ws;
    unsigned short* xbf  = (unsigned short*)w; w += (size_t)NN * H * 2;     // 17.9 MB
    unsigned short* aggn = (unsigned short*)w; w += (size_t)SEGN * H * 2;   // 17.9 MB
    int* gcur = (int*)w;            w += (size_t)NBUCK * SUBS * 4;          // 70 KB
    unsigned* pairs = (unsigned*)w; w += (size_t)NBUCK * BUCKCAP * 4;       // 22.4 MB

    init_gcur_kernel<<<(NBUCK * SUBS + 255) / 256, 256, 0, stream>>>(gcur);
    binpack_kernel<<<NBB, 512, 0, stream>>>(dst_pc, src_pc, dst_cp, src_cp, gcur, pairs);

    const int PB = (NPAT + BM - 1) / BM;  // 391
    const int CB = (NCON + BM - 1) / BM;  // 157

    // projections -> xbf only
    {
        GemmJob jp = { x_patient, W_p, b_p, xbf, 64, 64, NPAT };
        GemmJob jc = { x_concept, W_c, b_c, xbf + (size_t)NPAT * H, 128, 128, NCON };
        gemm_dual_kernel<<<PB + CB, 256, 0, stream>>>(jp, jc, PB);
    }

    for (int l = 0; l < 2; l++) {
        aggregate_kernel<<<NBUCK, 512, 0, stream>>>(xbf, pairs, gcur, aggn);
        const float* Wroot_l = W_root + (size_t)l * H * H;
        const float* Wrel_l0 = W_rel + (size_t)(l * 2 + 0) * H * H;
        const float* Wrel_l1 = W_rel + (size_t)(l * 2 + 1) * H * H;
        const float* br = b_root + (size_t)l * H;
        float* cp = (l == 1) ? out : nullptr;
        float* cc = (l == 1) ? out + (size_t)NPAT * H : nullptr;
        unsigned short* bp = (l == 0) ? xbf : nullptr;                       // in-place ok
        unsigned short* bc = (l == 0) ? xbf + (size_t)NPAT * H : nullptr;
        MJob jp = { xbf, aggn + (size_t)NCON_AL * H, Wroot_l, Wrel_l1, br,
                    cp, bp, NPAT };
        MJob jc = { xbf + (size_t)NPAT * H, aggn, Wroot_l, Wrel_l0, br,
                    cc, bc, NCON };
        gemm_mfma_kernel<<<PB + CB, 256, 0, stream>>>(jp, jc, PB);
    }
}

// Round 2
// 314.212 us; speedup vs baseline: 1.0578x; 1.0391x over previous
//
#include <hip/hip_runtime.h>
#include <hip/hip_bf16.h>

#define NPAT 50000
#define NCON 20000
#define NN   70000
#define EE   800000
#define H    128

#define NCON_AL  20032                 // concepts padded to 64-alignment
#define SEGN     (NCON_AL + NPAT)      // 70032 segment ids
#define NBUCK    1095                  // ceil(SEGN/64)
#define RELSPLIT_B 313                 // buckets [0,313) = concept dsts (rel0)
#define BUCKCAP  5120                  // pairs capacity per bucket (max fill ~2900)
#define SUBS     16                    // sub-regions per bucket (reservation slots)
#define SUBCAP   (BUCKCAP / SUBS)      // 320 (max fill ~236)
#define BPE      4096                  // edges per binpack block
#define NBB      ((2 * EE + BPE - 1) / BPE)   // 391
#define CAP      4096                  // sorted-src capacity per bucket (max ~2900)

typedef __attribute__((ext_vector_type(8))) short bf16x8;
typedef __attribute__((ext_vector_type(4))) float f32x4;

__device__ inline unsigned short f2bf(float f) {
    unsigned u = __float_as_uint(f);
    unsigned r = (u + 0x7FFFu + ((u >> 16) & 1u)) >> 16;
    return (unsigned short)r;
}
__device__ inline float bf2f_lo(unsigned v) { return __uint_as_float(v << 16); }
__device__ inline float bf2f_hi(unsigned v) { return __uint_as_float(v & 0xFFFF0000u); }

// ============ init: per-(bucket,sub) cursors at static bases ============
__global__ void init_gcur_kernel(int* __restrict__ gcur) {
    int j = blockIdx.x * 256 + threadIdx.x;
    if (j < NBUCK * SUBS) gcur[j] = (j >> 4) * BUCKCAP + (j & (SUBS - 1)) * SUBCAP;
}

// ============ binpack: 512 thr, LDS counting sort by bucket, run-reserve, write ====
__global__ __launch_bounds__(512) void binpack_kernel(
        const int* __restrict__ dst_pc, const int* __restrict__ src_pc,
        const int* __restrict__ dst_cp, const int* __restrict__ src_cp,
        int* __restrict__ gcur, unsigned* __restrict__ pairs) {
    __shared__ unsigned sval[BPE];           // 16 KB
    __shared__ unsigned short sbkt[BPE];     // 8 KB (bucket id per sorted slot)
    __shared__ int cnt[NBUCK];               // 4.4 KB (then local cursor)
    __shared__ int delta[NBUCK];             // 4.4 KB
    __shared__ int partial[512];
    int t = threadIdx.x, blk = blockIdx.x;
    int base = blk * BPE;
    int n = min(BPE, 2 * EE - base);

    for (int i = t; i < NBUCK; i += 512) cnt[i] = 0;
    __syncthreads();

    unsigned pay[8];
    int bkt[8];
#pragma unroll
    for (int q = 0; q < 8; q++) {
        int li = q * 512 + t;
        bkt[q] = -1;
        if (li < n) {
            int i = base + li;
            int seg, src;
            if (i < EE) { seg = dst_pc[i];                src = src_pc[i]; }
            else        { seg = NCON_AL + dst_cp[i - EE]; src = src_cp[i - EE]; }
            int b = seg >> 6;
            pay[q] = (unsigned)src | ((unsigned)(seg & 63) << 16);
            bkt[q] = b;
            atomicAdd(&cnt[b], 1);
        }
    }
    __syncthreads();

    const int PER = (NBUCK + 511) / 512;   // 3
    int beg = t * PER;
    int s = 0;
#pragma unroll
    for (int k = 0; k < PER; k++) { int i = beg + k; if (i < NBUCK) s += cnt[i]; }
    partial[t] = s;
    __syncthreads();
    for (int o = 1; o < 512; o <<= 1) {
        int v = (t >= o) ? partial[t - o] : 0;
        __syncthreads();
        partial[t] += v;
        __syncthreads();
    }
    int run = partial[t] - s;
    int sub = blk & (SUBS - 1);
    int prefk[PER];
#pragma unroll
    for (int k = 0; k < PER; k++) {
        int i = beg + k;
        if (i < NBUCK) {
            prefk[k] = run;
            int c = cnt[i];
            if (c > 0) {
                int gb = atomicAdd(&gcur[i * SUBS + sub], c);
                delta[i] = gb - run;
            }
            run += c;
        }
    }
    __syncthreads();
#pragma unroll
    for (int k = 0; k < PER; k++) { int i = beg + k; if (i < NBUCK) cnt[i] = prefk[k]; }
    __syncthreads();

#pragma unroll
    for (int q = 0; q < 8; q++) {
        if (bkt[q] >= 0) {
            int b = bkt[q];
            int pos = atomicAdd(&cnt[b], 1);
            sval[pos] = pay[q];
            sbkt[pos] = (unsigned short)b;
        }
    }
    __syncthreads();
    for (int i = t; i < n; i += 512)
        pairs[delta[sbkt[i]] + i] = sval[i];
}

// ============ build CSR per bucket (runs ONCE): count + scan + place, dump ========
// ssrc dump overwrites the bucket's own pairs region (reads all done pre-barrier).
__global__ __launch_bounds__(512) void build_ssrc_kernel(
        const unsigned* __restrict__ pairs, const int* __restrict__ gcur,
        int* __restrict__ soffg) {
    __shared__ int cnt64[64];
    __shared__ int soff[65];
    __shared__ int scur[64];
    __shared__ unsigned short ssrc[CAP];
    int t = threadIdx.x, b = blockIdx.x;
    if (t < 64) cnt64[t] = 0;
    __syncthreads();
    // pass A: count per-seg degree over the 16 sub-regions
    for (int s = 0; s < SUBS; s++) {
        int rbase = b * BUCKCAP + s * SUBCAP;
        int rcnt = gcur[b * SUBS + s] - rbase;
        for (int i = t; i < rcnt; i += 512)
            atomicAdd(&cnt64[pairs[rbase + i] >> 16], 1);
    }
    __syncthreads();
    if (t < 64) {  // wave 0: exclusive scan
        int v = cnt64[t];
        int s = v;
#pragma unroll
        for (int o = 1; o < 64; o <<= 1) {
            int u = __shfl_up(s, o);
            if (t >= o) s += u;
        }
        soff[t + 1] = s;
        if (t == 0) soff[0] = 0;
        scur[t] = s - v;
    }
    __syncthreads();
    // pass B: place srcs per-dst-contiguous
    for (int s = 0; s < SUBS; s++) {
        int rbase = b * BUCKCAP + s * SUBCAP;
        int rcnt = gcur[b * SUBS + s] - rbase;
        for (int i = t; i < rcnt; i += 512) {
            unsigned p = pairs[rbase + i];
            int pos = atomicAdd(&scur[p >> 16], 1);
            ssrc[pos] = (unsigned short)(p & 0xFFFF);
        }
    }
    __syncthreads();
    // dump: soff + sorted srcs (as uints) into this bucket's pairs region
    if (t < 65) soffg[b * 65 + t] = soff[t];
    int tot = soff[64];
    unsigned* sg = (unsigned*)(((unsigned short*)pairs) + (size_t)b * BUCKCAP * 2);
    const unsigned* sl = (const unsigned*)ssrc;
    for (int i = t; i < ((tot + 1) >> 1); i += 512) sg[i] = sl[i];
}

// ============ mean aggregation gather: block per bucket, 512 thr ============
// 16 lanes cover a 256B row (uint4/lane), 4 edge-slots per wave,
// 2-deep unroll -> 8 independent uint4 loads (32 B/lane) in flight.
#define ACC8(a0, a1, v) \
    a0.x += bf2f_lo((v).x); a0.y += bf2f_hi((v).x); \
    a0.z += bf2f_lo((v).y); a0.w += bf2f_hi((v).y); \
    a1.x += bf2f_lo((v).z); a1.y += bf2f_hi((v).z); \
    a1.z += bf2f_lo((v).w); a1.w += bf2f_hi((v).w);

__global__ __launch_bounds__(512) void gather_kernel(
        const unsigned short* __restrict__ xbf,
        const unsigned short* __restrict__ ssrcg,
        const int* __restrict__ soffg,
        unsigned short* __restrict__ aggn) {
    __shared__ int soff[65];
    __shared__ unsigned short ssrc[CAP];
    int t = threadIdx.x, b = blockIdx.x;
    if (t < 65) soff[t] = soffg[b * 65 + t];
    __syncthreads();
    int tot = soff[64];
    const unsigned* sg = (const unsigned*)(ssrcg + (size_t)b * BUCKCAP * 2);
    unsigned* sl = (unsigned*)ssrc;
    for (int i = t; i < ((tot + 1) >> 1); i += 512) sl[i] = sg[i];
    __syncthreads();
    // gather: 8 waves x 8 segs
    int wv = t >> 6, lane = t & 63;
    int g = lane >> 4;          // edge slot 0..3
    int q = lane & 15;          // uint4 index within row (16 B granule)
    int rowbase = (b < RELSPLIT_B) ? 0 : NPAT;
    int seglim  = (b < RELSPLIT_B) ? NCON : SEGN;
    const uint4* xw4 = (const uint4*)xbf;   // 16 x uint4 per row
    for (int i = 0; i < 8; i++) {
        int d = wv * 8 + i;
        int seg = b * 64 + d;
        if (seg >= seglim) continue;
        int beg = soff[d], end = soff[d + 1];
        float4 aA0 = {0.f, 0.f, 0.f, 0.f}, aA1 = {0.f, 0.f, 0.f, 0.f};
        float4 aB0 = {0.f, 0.f, 0.f, 0.f}, aB1 = {0.f, 0.f, 0.f, 0.f};
        int j = beg;
        for (; j + 7 < end; j += 8) {  // 8 edges via 2 independent uint4/lane
            int sA = ssrc[j + g];
            int sB = ssrc[j + 4 + g];
            uint4 vA = xw4[(size_t)(rowbase + sA) * 16 + q];
            uint4 vB = xw4[(size_t)(rowbase + sB) * 16 + q];
            ACC8(aA0, aA1, vA);
            ACC8(aB0, aB1, vB);
        }
        for (; j < end; j += 4) {      // tail: <=2 masked rounds of up to 4 edges
            if (g < end - j) {
                int s0 = ssrc[j + g];
                uint4 v = xw4[(size_t)(rowbase + s0) * 16 + q];
                ACC8(aA0, aA1, v);
            }
        }
        aA0.x += aB0.x; aA0.y += aB0.y; aA0.z += aB0.z; aA0.w += aB0.w;
        aA1.x += aB1.x; aA1.y += aB1.y; aA1.z += aB1.z; aA1.w += aB1.w;
        float r0 = aA0.x, r1 = aA0.y, r2 = aA0.z, r3 = aA0.w;
        float r4 = aA1.x, r5 = aA1.y, r6 = aA1.z, r7 = aA1.w;
        // reduce across the 4 edge-slots (lane bits 4 and 5)
        r0 += __shfl_xor(r0, 16); r1 += __shfl_xor(r1, 16);
        r2 += __shfl_xor(r2, 16); r3 += __shfl_xor(r3, 16);
        r4 += __shfl_xor(r4, 16); r5 += __shfl_xor(r5, 16);
        r6 += __shfl_xor(r6, 16); r7 += __shfl_xor(r7, 16);
        r0 += __shfl_xor(r0, 32); r1 += __shfl_xor(r1, 32);
        r2 += __shfl_xor(r2, 32); r3 += __shfl_xor(r3, 32);
        r4 += __shfl_xor(r4, 32); r5 += __shfl_xor(r5, 32);
        r6 += __shfl_xor(r6, 32); r7 += __shfl_xor(r7, 32);
        if (g == 0) {
            float inv = 1.0f / (float)max(end - beg, 1);
            uint4 o;
            o.x = (unsigned)f2bf(r0 * inv) | ((unsigned)f2bf(r1 * inv) << 16);
            o.y = (unsigned)f2bf(r2 * inv) | ((unsigned)f2bf(r3 * inv) << 16);
            o.z = (unsigned)f2bf(r4 * inv) | ((unsigned)f2bf(r5 * inv) << 16);
            o.w = (unsigned)f2bf(r6 * inv) | ((unsigned)f2bf(r7 * inv) << 16);
            *(uint4*)&aggn[(size_t)seg * H + 8 * q] = o;  // zero-deg segs write 0 (required)
        }
    }
}

// ============ proj GEMM (fp32 VALU): Cbf = A1 @ B1 + bias ============
#define BM 128
#define BK 8

struct GemmJob {
    const float* A1;
    const float* B1;
    const float* bias; unsigned short* Cbf;
    int lda1, K1, M;
};

__global__ void gemm_dual_kernel(GemmJob j0, GemmJob j1, int nb0) {
    __shared__ float sA[BK][BM];
    __shared__ float sB[BK][H];
    bool first = (int)blockIdx.x < nb0;
    GemmJob j = first ? j0 : j1;
    int bm = (first ? blockIdx.x : blockIdx.x - nb0) * BM;
    int tid = threadIdx.x;
    int am = tid >> 1;
    int ak = (tid & 1) * 4;
    int bk = tid >> 5;
    int bn = (tid & 31) * 4;
    int ty = tid >> 4;
    int tx = tid & 15;
    float acc[8][8] = {};
    for (int k0 = 0; k0 < j.K1; k0 += BK) {
        int gm = bm + am; if (gm >= j.M) gm = j.M - 1;
        float4 av = *(const float4*)&j.A1[(size_t)gm * j.lda1 + k0 + ak];
        float4 bv = *(const float4*)&j.B1[(size_t)(k0 + bk) * H + bn];
        __syncthreads();
        sA[ak + 0][am] = av.x; sA[ak + 1][am] = av.y;
        sA[ak + 2][am] = av.z; sA[ak + 3][am] = av.w;
        *(float4*)&sB[bk][bn] = bv;
        __syncthreads();
#pragma unroll
        for (int k = 0; k < BK; k++) {
            float a[8], bb[8];
            *(float4*)&a[0] = *(const float4*)&sA[k][ty * 8];
            *(float4*)&a[4] = *(const float4*)&sA[k][ty * 8 + 4];
            *(float4*)&bb[0] = *(const float4*)&sB[k][tx * 4];
            *(float4*)&bb[4] = *(const float4*)&sB[k][64 + tx * 4];
#pragma unroll
            for (int i = 0; i < 8; i++)
#pragma unroll
                for (int jj = 0; jj < 8; jj++)
                    acc[i][jj] += a[i] * bb[jj];
        }
    }
    float bcol[8];
    *(float4*)&bcol[0] = *(const float4*)&j.bias[tx * 4];
    *(float4*)&bcol[4] = *(const float4*)&j.bias[64 + tx * 4];
#pragma unroll
    for (int i = 0; i < 8; i++) {
        int gr = bm + ty * 8 + i;
        if (gr < j.M) {
#pragma unroll
            for (int q = 0; q < 8; q++) {
                float v = acc[i][q] + bcol[q];
                int gc = (q < 4) ? (tx * 4 + q) : (64 + tx * 4 + q - 4);
                j.Cbf[(size_t)gr * H + gc] = f2bf(v);
            }
        }
    }
}

// ============ layer GEMM (bf16 MFMA): C = [A1|A2] @ bf16([B1;B2]) + bias, relu ======
struct MJob {
    const unsigned short* A1;  // [M][H] bf16
    const unsigned short* A2;  // [M][H] bf16
    const float* B1;           // [H][H] fp32 k-major
    const float* B2;
    const float* bias;
    float* C;                  // fp32 or null
    unsigned short* Cbf;       // bf16 or null
    int M;
};

__global__ __launch_bounds__(256) void gemm_mfma_kernel(MJob j0, MJob j1, int nb0) {
    __shared__ unsigned short sA[128][40];   // [row][k] pad 32->40
    __shared__ unsigned short sBT[128][40];  // [col][k]
    bool first = (int)blockIdx.x < nb0;
    MJob J = first ? j0 : j1;
    int bm = (first ? (int)blockIdx.x : (int)blockIdx.x - nb0) * 128;
    int tid = threadIdx.x;
    int wv = tid >> 6, lane = tid & 63;
    int wr = wv >> 1, wc = wv & 1;
    int m16 = lane & 15, kg = lane >> 4;

    f32x4 acc[4][4];
#pragma unroll
    for (int a = 0; a < 4; a++)
#pragma unroll
        for (int c = 0; c < 4; c++) acc[a][c] = (f32x4){0.f, 0.f, 0.f, 0.f};

    int ar = tid >> 1, ah = tid & 1;
    int gmA = bm + ar; if (gmA >= J.M) gmA = J.M - 1;
    int bn = tid & 127, bk0 = tid >> 7;

#pragma unroll
    for (int kt = 0; kt < 8; kt++) {
        int k0 = kt * 32;
        const unsigned short* asrc = (k0 < 128)
            ? (J.A1 + (size_t)gmA * H + k0)
            : (J.A2 + (size_t)gmA * H + (k0 - 128));
        const uint4* a4 = (const uint4*)(asrc + ah * 16);
        uint4 av0 = a4[0], av1 = a4[1];
        const float* bsrc = (k0 < 128) ? (J.B1 + (size_t)k0 * H)
                                       : (J.B2 + (size_t)(k0 - 128) * H);
        float bvals[16];
#pragma unroll
        for (int kk = 0; kk < 16; kk++) bvals[kk] = bsrc[(size_t)(2 * kk + bk0) * H + bn];
        __syncthreads();
        { uint4* d4 = (uint4*)&sA[ar][ah * 16]; d4[0] = av0; d4[1] = av1; }
#pragma unroll
        for (int kk = 0; kk < 16; kk++) sBT[bn][2 * kk + bk0] = f2bf(bvals[kk]);
        __syncthreads();
        bf16x8 af[4], bfg[4];
#pragma unroll
        for (int mt = 0; mt < 4; mt++)
            af[mt] = *(bf16x8*)&sA[wr * 64 + mt * 16 + m16][kg * 8];
#pragma unroll
        for (int nt = 0; nt < 4; nt++)
            bfg[nt] = *(bf16x8*)&sBT[wc * 64 + nt * 16 + m16][kg * 8];
#pragma unroll
        for (int mt = 0; mt < 4; mt++)
#pragma unroll
            for (int nt = 0; nt < 4; nt++)
                acc[mt][nt] = __builtin_amdgcn_mfma_f32_16x16x32_bf16(
                    af[mt], bfg[nt], acc[mt][nt], 0, 0, 0);
    }
    float bv[4];
#pragma unroll
    for (int nt = 0; nt < 4; nt++) bv[nt] = J.bias[wc * 64 + nt * 16 + m16];
#pragma unroll
    for (int mt = 0; mt < 4; mt++) {
        int gr0 = bm + wr * 64 + mt * 16 + kg * 4;
#pragma unroll
        for (int r = 0; r < 4; r++) {
            int gr = gr0 + r;
            if (gr < J.M) {
#pragma unroll
                for (int nt = 0; nt < 4; nt++) {
                    int gc = wc * 64 + nt * 16 + m16;
                    float v = fmaxf(acc[mt][nt][r] + bv[nt], 0.f);
                    if (J.C)   J.C[(size_t)gr * H + gc] = v;
                    if (J.Cbf) J.Cbf[(size_t)gr * H + gc] = f2bf(v);
                }
            }
        }
    }
}

// ============ launch ============

extern "C" void kernel_launch(void* const* d_in, const int* in_sizes, int n_in,
                              void* d_out, int out_size, void* d_ws, size_t ws_size,
                              hipStream_t stream) {
    const float* x_patient = (const float*)d_in[0];
    const float* x_concept = (const float*)d_in[1];
    const float* W_p       = (const float*)d_in[2];
    const float* b_p       = (const float*)d_in[3];
    const float* W_c       = (const float*)d_in[4];
    const float* b_c       = (const float*)d_in[5];
    const float* W_root    = (const float*)d_in[6];
    const float* b_root    = (const float*)d_in[7];
    const float* W_rel     = (const float*)d_in[8];
    const int*   src_pc    = (const int*)d_in[9];
    const int*   dst_pc    = (const int*)d_in[10];
    const int*   src_cp    = (const int*)d_in[11];
    const int*   dst_cp    = (const int*)d_in[12];
    float* out = (float*)d_out;

    char* w = (char*)d_ws;
    unsigned short* xbf  = (unsigned short*)w; w += (size_t)NN * H * 2;     // 17.9 MB
    unsigned short* aggn = (unsigned short*)w; w += (size_t)SEGN * H * 2;   // 17.9 MB
    int* gcur = (int*)w;            w += (size_t)NBUCK * SUBS * 4;          // 70 KB
    unsigned* pairs = (unsigned*)w; w += (size_t)NBUCK * BUCKCAP * 4;       // 22.4 MB
    int* soffg = (int*)w;           w += (size_t)NBUCK * 65 * 4;            // 285 KB

    init_gcur_kernel<<<(NBUCK * SUBS + 255) / 256, 256, 0, stream>>>(gcur);
    binpack_kernel<<<NBB, 512, 0, stream>>>(dst_pc, src_pc, dst_cp, src_cp, gcur, pairs);
    build_ssrc_kernel<<<NBUCK, 512, 0, stream>>>(pairs, gcur, soffg);
    const unsigned short* ssrcg = (const unsigned short*)pairs;  // build dumped here

    const int PB = (NPAT + BM - 1) / BM;  // 391
    const int CB = (NCON + BM - 1) / BM;  // 157

    // projections -> xbf only
    {
        GemmJob jp = { x_patient, W_p, b_p, xbf, 64, 64, NPAT };
        GemmJob jc = { x_concept, W_c, b_c, xbf + (size_t)NPAT * H, 128, 128, NCON };
        gemm_dual_kernel<<<PB + CB, 256, 0, stream>>>(jp, jc, PB);
    }

    for (int l = 0; l < 2; l++) {
        gather_kernel<<<NBUCK, 512, 0, stream>>>(xbf, ssrcg, soffg, aggn);
        const float* Wroot_l = W_root + (size_t)l * H * H;
        const float* Wrel_l0 = W_rel + (size_t)(l * 2 + 0) * H * H;
        const float* Wrel_l1 = W_rel + (size_t)(l * 2 + 1) * H * H;
        const float* br = b_root + (size_t)l * H;
        float* cp = (l == 1) ? out : nullptr;
        float* cc = (l == 1) ? out + (size_t)NPAT * H : nullptr;
        unsigned short* bp = (l == 0) ? xbf : nullptr;                       // in-place ok
        unsigned short* bc = (l == 0) ? xbf + (size_t)NPAT * H : nullptr;
        MJob jp = { xbf, aggn + (size_t)NCON_AL * H, Wroot_l, Wrel_l1, br,
                    cp, bp, NPAT };
        MJob jc = { xbf + (size_t)NPAT * H, aggn, Wroot_l, Wrel_l0, br,
                    cc, bc, NCON };
        gemm_mfma_kernel<<<PB + CB, 256, 0, stream>>>(jp, jc, PB);
    }
}